// Round 8
// baseline (258.392 us; speedup 1.0000x reference)
//
#include <hip/hip_runtime.h>
#include <hip/hip_bf16.h>

typedef unsigned short u16;
typedef unsigned long long u64;
typedef __bf16 bf16x8 __attribute__((ext_vector_type(8)));
typedef float f32x4 __attribute__((ext_vector_type(4)));

// ---------- helpers ----------
__device__ __forceinline__ void async16(const void* g, void* l) {
  __builtin_amdgcn_global_load_lds((const __attribute__((address_space(1))) void*)g,
                                   (__attribute__((address_space(3))) void*)l, 16, 0, 0);
}
__device__ __forceinline__ u16 f2bf(float f) {
  __hip_bfloat16 h = __float2bfloat16(f);
  u16 u; __builtin_memcpy(&u, &h, 2); return u;
}

// ---------- fused weight convert + pad (fp32 -> bf16, zero pad) ----------
__global__ __launch_bounds__(256) void convert_all(
    const float* __restrict__ W1, const float* __restrict__ W2,
    const float* __restrict__ W3, const float* __restrict__ W4,
    u16* __restrict__ w1b, u16* __restrict__ w2b,
    u16* __restrict__ w3b, u16* __restrict__ w4b) {
  int bx = blockIdx.x;
  const float* src; u16* dst; int R, C, Cp, base;
  if (bx < 800)       { src = W1; dst = w1b; R = 256; C = 784; Cp = 800; base = 0; }
  else if (bx < 1056) { src = W2; dst = w2b; R = 256; C = 256; Cp = 256; base = 800; }
  else if (bx < 1312) { src = W3; dst = w3b; R = 256; C = 256; Cp = 256; base = 1056; }
  else                { src = W4; dst = w4b; R = 10;  C = 256; Cp = 256; base = 1312; }
  int idx = (bx - base) * 256 + threadIdx.x;
  int r = idx / Cp, c = idx - r * Cp;
  float v = (r < R && c < C) ? src[(size_t)r * C + c] : 0.0f;
  dst[idx] = f2bf(v);
}

// ---------- fully-fused forward: 64 rows/block, 8 waves, 2 blocks/CU ----------
// Layer-1 A comes straight from global x (fp32) into register fragments:
// lane (lm,q) loads x[row][kc*32+q*8 .. +7] (two float4s, full 128B-line use
// per 16-row group), converts to bf16 in-VGPR. bits0 = ballots on the frag
// registers ((short)bf16bits > 0 == fp32 x>0 for all normal values).
// LDS = hbuf 40K + Wt 32K = 72 KB -> 2 blocks/CU.
__global__ __launch_bounds__(512, 4) void fwd_fused(
    const float* __restrict__ x,
    const u16* __restrict__ W1b, const float* __restrict__ b1,
    const u16* __restrict__ W2b, const float* __restrict__ b2,
    const u16* __restrict__ W3b, const float* __restrict__ b3,
    const u16* __restrict__ W4b, const float* __restrict__ b4,
    float* __restrict__ out,
    u64* __restrict__ bits0, u64* __restrict__ bits1,
    u64* __restrict__ bits2, u64* __restrict__ bits3,
    u64* __restrict__ bits4) {

  __shared__ __align__(16) u16 hbuf[8 * 64 * 40];  // 40 KB: 8 kt-tiles [64 rows][32+8 pad]
  __shared__ __align__(16) u16 Wt[2][256 * 32];    // 32 KB: W tile dbuf
  __shared__ __align__(16) float Ls[64 * 12];      // 3 KB: logits scratch

  const int tid = threadIdx.x;
  const int lane = tid & 63, wv = tid >> 6;        // 8 waves
  const int lm = lane & 15, q = lane >> 4;
  const int m0 = blockIdx.x * 64;
  const int wm = (wv & 1) * 32;                    // rows 0/32
  const int wn = (wv >> 1) * 64;                   // cols 0/64/128/192

  auto stageW = [&](const u16* W, int K, int kc, u16* dst) {
    #pragma unroll
    for (int i = 0; i < 2; i++) {
      int seg = i * 512 + tid;
      int n = seg >> 2, kq = seg & 3;
      async16(W + (size_t)n * K + kc * 32 + kq * 8, dst + seg * 8);
    }
  };
  auto stageW4 = [&]() {   // W4b [16][256] -> Wt[1] CONTIGUOUS (lane-linear dest!)
    if (tid < 512) async16(W4b + tid * 8, Wt[1] + tid * 8);
  };
  // operand-swapped epilogue: lane (lm,q) holds rows wm+mi*16+lm, cols wn+ni*16+q*4..+3
  auto epilogue = [&](f32x4 (&acc)[2][4], const float* __restrict__ bias) {
    #pragma unroll
    for (int mi = 0; mi < 2; mi++) {
      int row = wm + mi * 16 + lm;
      #pragma unroll
      for (int ni = 0; ni < 4; ni++) {
        int col = wn + ni * 16 + q * 4;
        float4 bv = *(const float4*)(bias + col);
        float h0 = acc[mi][ni][0] + bv.x; h0 = h0 > 0.0f ? h0 : 0.0f;
        float h1 = acc[mi][ni][1] + bv.y; h1 = h1 > 0.0f ? h1 : 0.0f;
        float h2 = acc[mi][ni][2] + bv.z; h2 = h2 > 0.0f ? h2 : 0.0f;
        float h3 = acc[mi][ni][3] + bv.w; h3 = h3 > 0.0f ? h3 : 0.0f;
        ushort4 o = {f2bf(h0), f2bf(h1), f2bf(h2), f2bf(h3)};
        int kt = col >> 5, cin = col & 31;
        *(ushort4*)(hbuf + kt * 2560 + row * 40 + cin) = o;
      }
    }
  };
  // conflict-free bitpack of hbuf: wave wv handles kt=wv; lane = row
  auto ballot_pass = [&](u64* bits) {
    u64 my = 0;
    #pragma unroll
    for (int g = 0; g < 4; g++) {
      ushort4 v0 = *(const ushort4*)(hbuf + wv * 2560 + lane * 40 + g * 8);
      ushort4 v1 = *(const ushort4*)(hbuf + wv * 2560 + lane * 40 + g * 8 + 4);
      u16 s[8] = {v0.x, v0.y, v0.z, v0.w, v1.x, v1.y, v1.z, v1.w};
      #pragma unroll
      for (int j = 0; j < 8; j++) {
        u64 m = __ballot(s[j] != 0);
        if (lane == g * 8 + j) my = m;
      }
    }
    if (lane < 32) bits[(size_t)blockIdx.x * 256 + wv * 32 + lane] = my;
  };

  // ---- layer 1: K=800 (784 real), A from global x via registers ----
  {
    f32x4 acc[2][4] = {};
    float4 xv[2][2];   // next k-chunk's fp32 fragment halves [mi][half]
    bf16x8 hA[2];      // current k-chunk's bf16 A-fragments
    const int arow = m0 + wm + lm;

    auto loadX = [&](int kc) {
      int col = kc * 32 + q * 8;
      bool ok = col + 7 < 784;
      #pragma unroll
      for (int mi = 0; mi < 2; mi++) {
        if (ok) {
          const float* src = x + (size_t)(arow + mi * 16) * 784 + col;
          xv[mi][0] = *(const float4*)src;
          xv[mi][1] = *(const float4*)(src + 4);
        } else {
          xv[mi][0] = float4{0, 0, 0, 0};
          xv[mi][1] = float4{0, 0, 0, 0};
        }
      }
    };
    auto cvtX = [&]() {
      #pragma unroll
      for (int mi = 0; mi < 2; mi++) {
        union { bf16x8 v; u16 s[8]; } u;
        u.s[0] = f2bf(xv[mi][0].x); u.s[1] = f2bf(xv[mi][0].y);
        u.s[2] = f2bf(xv[mi][0].z); u.s[3] = f2bf(xv[mi][0].w);
        u.s[4] = f2bf(xv[mi][1].x); u.s[5] = f2bf(xv[mi][1].y);
        u.s[6] = f2bf(xv[mi][1].z); u.s[7] = f2bf(xv[mi][1].w);
        hA[mi] = u.v;
      }
    };
    // bits0 from current frags: waves 0,1 (wn==0) cover rows 0..63 in 16-bit pieces
    auto emitBits0 = [&](int kc) {
      if (wv >= 2) return;                     // wave-uniform branch
      u16* b16 = (u16*)bits0;
      #pragma unroll
      for (int mi = 0; mi < 2; mi++) {
        union { bf16x8 v; short s[8]; } u; u.v = hA[mi];
        int piece = (wm + mi * 16) >> 4;
        #pragma unroll
        for (int j = 0; j < 8; j++) {
          u64 m = __ballot(u.s[j] > 0);        // bf16 sign+nonzero == fp32 x>0
          int col = kc * 32 + q * 8 + j;
          if (lm == j && col < 784)
            b16[((size_t)blockIdx.x * 784 + col) * 4 + piece] = (u16)(m >> (q * 16));
        }
      }
    };

    stageW(W1b, 800, 0, Wt[0]);
    loadX(0);
    cvtX();
    for (int kc = 0; kc < 25; kc++) {
      int cur = kc & 1;
      __syncthreads();   // drains Wt staging issued one full compute phase ago
      if (kc < 24) { stageW(W1b, 800, kc + 1, Wt[1 - cur]); loadX(kc + 1); }
      else         { stageW(W2b, 256, 0, Wt[1]); }          // cur=0 at kc=24
      bf16x8 w[4];
      #pragma unroll
      for (int ni = 0; ni < 4; ni++) w[ni] = *(const bf16x8*)(Wt[cur] + (wn + ni * 16 + lm) * 32 + q * 8);
      #pragma unroll
      for (int mi = 0; mi < 2; mi++)
        #pragma unroll
        for (int ni = 0; ni < 4; ni++)
          acc[mi][ni] = __builtin_amdgcn_mfma_f32_16x16x32_bf16(w[ni], hA[mi], acc[mi][ni], 0, 0, 0);
      emitBits0(kc);                            // ballots on current frags
      if (kc < 24) cvtX();                      // then overwrite with next
    }
    __syncthreads();
    epilogue(acc, b1);
  }
  __syncthreads();
  ballot_pass(bits1);

  // ---- layers 2,3: K=256, A from hbuf ----
  auto layer256 = [&](const u16* Wthis, const u16* Wnext, bool nextIsW4,
                      const float* __restrict__ bias, u64* bits) {
    f32x4 acc[2][4] = {};
    for (int kc = 0; kc < 8; kc++) {
      int cur = (kc & 1) ^ 1;
      __syncthreads();
      if (kc < 7)       stageW(Wthis, 256, kc + 1, Wt[cur ^ 1]);
      else if (nextIsW4) stageW4();                          // cur=0 at kc=7 -> Wt[1]
      else              stageW(Wnext, 256, 0, Wt[cur ^ 1]);
      bf16x8 w[4], h[2];
      #pragma unroll
      for (int ni = 0; ni < 4; ni++) w[ni] = *(const bf16x8*)(Wt[cur] + (wn + ni * 16 + lm) * 32 + q * 8);
      #pragma unroll
      for (int mi = 0; mi < 2; mi++) h[mi] = *(const bf16x8*)(hbuf + kc * 2560 + (wm + mi * 16 + lm) * 40 + q * 8);
      #pragma unroll
      for (int mi = 0; mi < 2; mi++)
        #pragma unroll
        for (int ni = 0; ni < 4; ni++)
          acc[mi][ni] = __builtin_amdgcn_mfma_f32_16x16x32_bf16(w[ni], h[mi], acc[mi][ni], 0, 0, 0);
    }
    __syncthreads();     // all hbuf reads complete before overwrite
    epilogue(acc, bias);
    __syncthreads();
    ballot_pass(bits);
  };
  layer256(W2b, W3b, false, b2, bits2);
  layer256(W3b, W4b, true,  b3, bits3);

  // ---- logits: waves 0..3, 16 rows each; W4 in Wt[1] contiguous [16][256] ----
  if (wv < 4) {
    const int r0 = wv * 16;
    f32x4 acc = {};
    #pragma unroll
    for (int kc = 0; kc < 8; kc++) {
      bf16x8 wf = *(const bf16x8*)(Wt[1] + lm * 256 + kc * 32 + q * 8);
      bf16x8 hf = *(const bf16x8*)(hbuf + kc * 2560 + (r0 + lm) * 40 + q * 8);
      acc = __builtin_amdgcn_mfma_f32_16x16x32_bf16(wf, hf, acc, 0, 0, 0);
    }
    // lane (lm,q): row = r0+lm, classes q*4..q*4+3
    int row = r0 + lm;
    float4 v;
    #pragma unroll
    for (int r = 0; r < 4; r++) {
      int c = q * 4 + r;
      float bv = (c < 10) ? b4[c] : 0.0f;
      v[r] = acc[r] + bv;
    }
    if (q < 3) *(float4*)(Ls + row * 12 + q * 4) = v;
    size_t ob = (size_t)(m0 + row) * 10;
    if (q < 2) {
      *(float2*)(out + ob + q * 4)     = make_float2(v[0], v[1]);
      *(float2*)(out + ob + q * 4 + 2) = make_float2(v[2], v[3]);
    } else if (q == 2) {
      *(float2*)(out + ob + 8) = make_float2(v[0], v[1]);
    }
  }
  __syncthreads();
  if (wv == 0) {
    float4 c03 = *(const float4*)(Ls + lane * 12);
    float4 c47 = *(const float4*)(Ls + lane * 12 + 4);
    float2 c89 = *(const float2*)(Ls + lane * 12 + 8);
    float s[10] = {c03.x, c03.y, c03.z, c03.w, c47.x, c47.y, c47.z, c47.w, c89.x, c89.y};
    u64 my = 0;
    #pragma unroll
    for (int c = 0; c < 10; c++) {
      u64 m = __ballot(s[c] > 0.0f);
      if (lane == c) my = m;
    }
    if (lane < 10) bits4[(size_t)blockIdx.x * 10 + lane] = my;
  }
}

// ---------- fused coactivations: grid (88, 16), 32 chunks/block ----------
__global__ __launch_bounds__(256) void coact_all(
    const u64* __restrict__ bits0, const u64* __restrict__ bits1,
    const u64* __restrict__ bits2, const u64* __restrict__ bits3,
    const u64* __restrict__ bits4, float* __restrict__ out) {
  const int bx = blockIdx.x;
  const u64 *bp, *bc; float* Cm; int FP, FC, i0, j0;
  if (bx < 52)      { bp = bits0; bc = bits1; Cm = out + 327680; FP = 784; FC = 256;
                      i0 = (bx % 13) * 64; j0 = (bx / 13) * 64; }
  else if (bx < 68) { int t = bx - 52; bp = bits1; bc = bits2; Cm = out + 528384; FP = 256; FC = 256;
                      i0 = (t & 3) * 64; j0 = (t >> 2) * 64; }
  else if (bx < 84) { int t = bx - 68; bp = bits2; bc = bits3; Cm = out + 593920; FP = 256; FC = 256;
                      i0 = (t & 3) * 64; j0 = (t >> 2) * 64; }
  else              { int t = bx - 84; bp = bits3; bc = bits4; Cm = out + 659456; FP = 256; FC = 10;
                      i0 = t * 64; j0 = 0; }

  __shared__ u64 Ps[16 * 64];
  __shared__ u64 Cs[16 * 64];
  const int tid = threadIdx.x;
  const int ch0 = blockIdx.y * 32;
  const int ti = tid >> 4, tj = tid & 15;
  unsigned cnt[4][4] = {};

  for (int s = 0; s < 2; s++) {
    int cb = ch0 + s * 16;
    #pragma unroll
    for (int r = 0; r < 4; r++) {
      int l = r * 256 + tid;
      int c = l >> 6, f = l & 63;
      Ps[l] = (i0 + f < FP) ? bp[(size_t)(cb + c) * FP + i0 + f] : 0ULL;
      Cs[l] = (j0 + f < FC) ? bc[(size_t)(cb + c) * FC + j0 + f] : 0ULL;
    }
    __syncthreads();
    #pragma unroll 4
    for (int c = 0; c < 16; c++) {
      u64 pv[4], cv[4];
      #pragma unroll
      for (int a = 0; a < 4; a++) pv[a] = Ps[c * 64 + a * 16 + ti];
      #pragma unroll
      for (int b = 0; b < 4; b++) cv[b] = Cs[c * 64 + b * 16 + tj];
      #pragma unroll
      for (int a = 0; a < 4; a++)
        #pragma unroll
        for (int b = 0; b < 4; b++)
          cnt[a][b] += (unsigned)__builtin_popcountll(pv[a] & cv[b]);
    }
    __syncthreads();
  }

  #pragma unroll
  for (int a = 0; a < 4; a++) {
    int i = i0 + a * 16 + ti;
    if (i >= FP) continue;
    #pragma unroll
    for (int b = 0; b < 4; b++) {
      int j = j0 + b * 16 + tj;
      if (j < FC) atomicAdd(&Cm[(size_t)i * FC + j], (float)cnt[a][b]);
    }
  }
}

// ---------- launch ----------
extern "C" void kernel_launch(void* const* d_in, const int* in_sizes, int n_in,
                              void* d_out, int out_size, void* d_ws, size_t ws_size,
                              hipStream_t stream) {
  const float* x  = (const float*)d_in[0];
  const float* W1 = (const float*)d_in[1];
  const float* b1 = (const float*)d_in[2];
  const float* W2 = (const float*)d_in[3];
  const float* b2 = (const float*)d_in[4];
  const float* W3 = (const float*)d_in[5];
  const float* b3 = (const float*)d_in[6];
  const float* W4 = (const float*)d_in[7];
  const float* b4 = (const float*)d_in[8];
  float* out = (float*)d_out;

  constexpr size_t O_C0 = 327680, O_END = 662016;

  char* p = (char*)d_ws;
  u16* w1b  = (u16*)p;  p += (size_t)256 * 800 * 2;
  u16* w2b  = (u16*)p;  p += (size_t)256 * 256 * 2;
  u16* w3b  = (u16*)p;  p += (size_t)256 * 256 * 2;
  u16* w4b  = (u16*)p;  p += (size_t)16 * 256 * 2;
  u64* bits0 = (u64*)p; p += (size_t)512 * 784 * 8;
  u64* bits1 = (u64*)p; p += (size_t)512 * 256 * 8;
  u64* bits2 = (u64*)p; p += (size_t)512 * 256 * 8;
  u64* bits3 = (u64*)p; p += (size_t)512 * 256 * 8;
  u64* bits4 = (u64*)p; p += (size_t)512 * 10 * 8;

  hipMemsetAsync((void*)(out + O_C0), 0, (O_END - O_C0) * sizeof(float), stream);

  convert_all<<<1328, 256, 0, stream>>>(W1, W2, W3, W4, w1b, w2b, w3b, w4b);

  fwd_fused<<<512, 512, 0, stream>>>(x, w1b, b1, w2b, b2, w3b, b3, w4b, b4,
                                     out, bits0, bits1, bits2, bits3, bits4);

  coact_all<<<dim3(88, 16), 256, 0, stream>>>(bits0, bits1, bits2, bits3, bits4, out);
}